// Round 3
// baseline (387.009 us; speedup 1.0000x reference)
//
#include <hip/hip_runtime.h>

#define N  160
#define SX (N * N)
#define SY N

typedef float f4 __attribute__((ext_vector_type(4)));

__device__ __forceinline__ f4 ld4(const float* __restrict__ p) {
    return *(const f4* __restrict__)p;
}

// 6-wide z-array: elements 0..5 hold F at z = zb-1 .. zb+4, with clamp
// semantics (elem0 = F[zb] when zb==0, elem5 = F[zb+3] when zb+4 > 159).
// Halo elements are fetched with clamped SCALAR loads — they hit cache
// lines already fetched by adjacent lanes of the same row. (Round-2 used
// __shfl, which breaks because row width 40 doesn't divide wave size 64:
// lane seams fall mid-row at (y,tx)=(1,24),(3,8),(4,32),(6,16).)
struct A6 { float v[6]; };

__device__ __forceinline__ A6 ld6(const float* __restrict__ p, int base, int tx) {
    A6 a;
    f4 c = ld4(p + base);
    a.v[1] = c.x; a.v[2] = c.y; a.v[3] = c.z; a.v[4] = c.w;
    a.v[0] = (tx > 0)  ? p[base - 1] : c.x;
    a.v[5] = (tx < 39) ? p[base + 4] : c.w;
    return a;
}

__global__ __launch_bounds__(320) void piano_energy_kernel(
    const float* __restrict__ C,   const float* __restrict__ Vx,
    const float* __restrict__ Vy,  const float* __restrict__ Vz,
    const float* __restrict__ Dxx, const float* __restrict__ Dxy,
    const float* __restrict__ Dxz, const float* __restrict__ Dyy,
    const float* __restrict__ Dyz, const float* __restrict__ Dzz,
    float* __restrict__ out)
{
    const int tx = threadIdx.x;                 // z-quad index 0..39
    const int zb = tx * 4;
    const int y  = blockIdx.y * 8 + threadIdx.y;
    const int x  = blockIdx.x;                  // block-uniform
    const int b  = blockIdx.z;
    const int idx = ((b * N + x) * N + y) * N + zb;

    const bool xlo = (x > 0), xhi = (x < N - 1);
    const bool ylo = (y > 0), yhi = (y < N - 1);

    const int oxp = xhi ? SX : 0,  oxm = xlo ? -SX : 0;
    const int oyp = yhi ? SY : 0,  oym = ylo ? -SY : 0;
    const float sxs = (xlo && xhi) ? 0.5f : 1.f;
    const float sys = (ylo && yhi) ? 0.5f : 1.f;

    // ========== phase 1: xy-plane cross terms (generic 4-combo form) ==========
    const int obx1 = xlo ? 0 : SX,  obx0 = obx1 - SX;
    const int oby1 = ylo ? 0 : SY,  oby0 = oby1 - SY;
    const int ofxp = oxp,           ofx0 = xhi ? 0 : -SX;
    const int ofyp = oyp,           ofy0 = yhi ? 0 : -SY;

    f4 xyA = ld4(C + idx + obx1 + ofyp);
    f4 xyB = ld4(C + idx + obx1 + ofy0);
    f4 xyC = ld4(C + idx + obx0 + ofyp);
    f4 xyD = ld4(C + idx + obx0 + ofy0);
    f4 yxA = ld4(C + idx + oby1 + ofxp);
    f4 yxB = ld4(C + idx + oby1 + ofx0);
    f4 yxC = ld4(C + idx + oby0 + ofxp);
    f4 yxD = ld4(C + idx + oby0 + ofx0);

    float cXY[4];   // crossXY + crossYX  (multiplied by Dxy later)
#pragma unroll
    for (int j = 0; j < 4; ++j)
        cXY[j] = (xyA[j] - xyB[j]) - (xyC[j] - xyD[j])
               + (yxA[j] - yxB[j]) - (yxC[j] - yxD[j]);

    // ========== phase 2: C z-arrays, first/second derivatives ==========
    A6 cc  = ld6(C, idx,       tx);
    A6 cxp = ld6(C, idx + oxp, tx);
    A6 cxm = ld6(C, idx + oxm, tx);
    A6 cyp = ld6(C, idx + oyp, tx);
    A6 cym = ld6(C, idx + oym, tx);

    f4 cx2 = 0, cy2 = 0;
    if (x == 0) cx2 = ld4(C + idx + 2 * SX);   // block-uniform branch
    if (y == 0) cy2 = ld4(C + idx + 2 * SY);   // rare divergent branch

    // forward first-diffs along x/y over all 6 z elements (for backward-z crosses)
    float gX[6], gY[6];
#pragma unroll
    for (int k = 0; k < 6; ++k) {
        gX[k] = xhi ? (cxp.v[k] - cc.v[k]) : (cc.v[k] - cxm.v[k]);
        gY[k] = yhi ? (cyp.v[k] - cc.v[k]) : (cc.v[k] - cym.v[k]);
    }

    float c0[4], fxp[4], fxm[4], fyp[4], fym[4], fzp[4], fzm[4];
    float Cxc[4], Cyc[4], Czc[4], sXX[4], sYY[4], sZZ[4], cXZ[4], cYZ[4];

#pragma unroll
    for (int j = 0; j < 4; ++j) {
        const int z = zb + j;
        const bool zbot = (z == 0), ztop = (z == N - 1);

        c0[j]  = cc.v[j + 1];
        fxp[j] = cxp.v[j + 1]; fxm[j] = cxm.v[j + 1];
        fyp[j] = cyp.v[j + 1]; fym[j] = cym.v[j + 1];
        fzp[j] = cc.v[j + 2];  fzm[j] = cc.v[j];

        const float szs = (zbot || ztop) ? 1.f : 0.5f;
        Cxc[j] = sxs * (fxp[j] - fxm[j]);
        Cyc[j] = sys * (fyp[j] - fym[j]);
        Czc[j] = szs * (fzp[j] - fzm[j]);

        // pure second derivatives  dAb(CA_f)
        sXX[j] = !xhi ? 0.f : (xlo ? (fxp[j] - 2.f * c0[j] + fxm[j])
                                   : (cx2[j] - 2.f * fxp[j] + c0[j]));
        sYY[j] = !yhi ? 0.f : (ylo ? (fyp[j] - 2.f * c0[j] + fym[j])
                                   : (cy2[j] - 2.f * fyp[j] + c0[j]));
        sZZ[j] = ztop ? 0.f : (!zbot ? (fzp[j] - 2.f * c0[j] + fzm[j])
                                     : (cc.v[3] - 2.f * cc.v[2] + cc.v[1]));

        // crossZX / crossZY : backward-z of gX / gY
        const float zx = zbot ? (gX[j + 2] - gX[j + 1]) : (gX[j + 1] - gX[j]);
        const float zy = zbot ? (gY[j + 2] - gY[j + 1]) : (gY[j + 1] - gY[j]);

        // crossXZ / crossYZ : backward-x/y of forward-z diff
#define FZD(P) (ztop ? (P.v[j + 1] - P.v[j]) : (P.v[j + 2] - P.v[j + 1]))
        const float xz = xlo ? (FZD(cc) - FZD(cxm)) : (FZD(cxp) - FZD(cc));
        const float yz = ylo ? (FZD(cc) - FZD(cym)) : (FZD(cyp) - FZD(cc));
#undef FZD
        cXZ[j] = zx + xz;   // × Dxz
        cYZ[j] = zy + yz;   // × Dyz
    }

    // ========== phase 3: advection ==========
    float res[4];
    {
        f4 vxc = ld4(Vx + idx), vxp = ld4(Vx + idx + oxp), vxm = ld4(Vx + idx + oxm);
        f4 vyc = ld4(Vy + idx), vyp = ld4(Vy + idx + oyp), vym = ld4(Vy + idx + oym);
        A6 vz6 = ld6(Vz, idx, tx);
#pragma unroll
        for (int j = 0; j < 4; ++j) {
            const int z = zb + j;
            const bool zbot = (z == 0), ztop = (z == N - 1);
            const float szs = (zbot || ztop) ? 1.f : 0.5f;

            const float dVx = sxs * (vxp[j] - vxm[j]);
            const float dVy = sys * (vyp[j] - vym[j]);
            const float dVz = szs * (vz6.v[j + 2] - vz6.v[j]);

            const float Cxf = xhi  ? (fxp[j] - c0[j]) : (c0[j] - fxm[j]);
            const float Cxb = xlo  ? (c0[j] - fxm[j]) : (fxp[j] - c0[j]);
            const float Cyf = yhi  ? (fyp[j] - c0[j]) : (c0[j] - fym[j]);
            const float Cyb = ylo  ? (c0[j] - fym[j]) : (fyp[j] - c0[j]);
            const float Czf = ztop ? (c0[j] - fzm[j]) : (fzp[j] - c0[j]);
            const float Czb = zbot ? (fzp[j] - c0[j]) : (c0[j] - fzm[j]);

            const float C_x = (vxc[j] > 0.f) ? Cxb : Cxf;
            const float C_y = (vyc[j] > 0.f) ? Cyb : Cyf;
            const float C_z = (vz6.v[j + 1] > 0.f) ? Czb : Czf;

            res[j] = -(vxc[j] * C_x + vyc[j] * C_y + vz6.v[j + 1] * C_z)
                   - c0[j] * (dVx + dVy + dVz);
        }
    }

    // ========== phase 4: diffusion, one D field at a time ==========
    {   // Dxx:  dXc(Dxx)*Cxc + Dxx*sXX
        f4 dc = ld4(Dxx + idx), dp = ld4(Dxx + idx + oxp), dm = ld4(Dxx + idx + oxm);
#pragma unroll
        for (int j = 0; j < 4; ++j)
            res[j] += sxs * (dp[j] - dm[j]) * Cxc[j] + dc[j] * sXX[j];
    }
    {   // Dyy
        f4 dc = ld4(Dyy + idx), dp = ld4(Dyy + idx + oyp), dm = ld4(Dyy + idx + oym);
#pragma unroll
        for (int j = 0; j < 4; ++j)
            res[j] += sys * (dp[j] - dm[j]) * Cyc[j] + dc[j] * sYY[j];
    }
    {   // Dzz
        A6 d6 = ld6(Dzz, idx, tx);
#pragma unroll
        for (int j = 0; j < 4; ++j) {
            const int z = zb + j;
            const float szs = (z == 0 || z == N - 1) ? 1.f : 0.5f;
            res[j] += szs * (d6.v[j + 2] - d6.v[j]) * Czc[j] + d6.v[j + 1] * sZZ[j];
        }
    }
    {   // Dxy:  dXc(Dxy)*Cyc + dYc(Dxy)*Cxc + Dxy*(crossXY+crossYX)
        f4 dc = ld4(Dxy + idx);
        f4 dxp = ld4(Dxy + idx + oxp), dxm = ld4(Dxy + idx + oxm);
        f4 dyp = ld4(Dxy + idx + oyp), dym = ld4(Dxy + idx + oym);
#pragma unroll
        for (int j = 0; j < 4; ++j)
            res[j] += sxs * (dxp[j] - dxm[j]) * Cyc[j]
                    + sys * (dyp[j] - dym[j]) * Cxc[j]
                    + dc[j] * cXY[j];
    }
    {   // Dxz:  dXc(Dxz)*Czc + dZc(Dxz)*Cxc + Dxz*(crossZX+crossXZ)
        A6 d6 = ld6(Dxz, idx, tx);
        f4 dp = ld4(Dxz + idx + oxp), dm = ld4(Dxz + idx + oxm);
#pragma unroll
        for (int j = 0; j < 4; ++j) {
            const int z = zb + j;
            const float szs = (z == 0 || z == N - 1) ? 1.f : 0.5f;
            res[j] += sxs * (dp[j] - dm[j]) * Czc[j]
                    + szs * (d6.v[j + 2] - d6.v[j]) * Cxc[j]
                    + d6.v[j + 1] * cXZ[j];
        }
    }
    {   // Dyz:  dYc(Dyz)*Czc + dZc(Dyz)*Cyc + Dyz*(crossYZ+crossZY)
        A6 d6 = ld6(Dyz, idx, tx);
        f4 dp = ld4(Dyz + idx + oyp), dm = ld4(Dyz + idx + oym);
#pragma unroll
        for (int j = 0; j < 4; ++j) {
            const int z = zb + j;
            const float szs = (z == 0 || z == N - 1) ? 1.f : 0.5f;
            res[j] += sys * (dp[j] - dm[j]) * Czc[j]
                    + szs * (d6.v[j + 2] - d6.v[j]) * Cyc[j]
                    + d6.v[j + 1] * cYZ[j];
        }
    }

    f4 o;
    o.x = res[0]; o.y = res[1]; o.z = res[2]; o.w = res[3];
    *(f4*)(out + idx) = o;
}

extern "C" void kernel_launch(void* const* d_in, const int* in_sizes, int n_in,
                              void* d_out, int out_size, void* d_ws, size_t ws_size,
                              hipStream_t stream) {
    const float* C   = (const float*)d_in[0];
    const float* Vx  = (const float*)d_in[1];
    const float* Vy  = (const float*)d_in[2];
    const float* Vz  = (const float*)d_in[3];
    const float* Dxx = (const float*)d_in[4];
    const float* Dxy = (const float*)d_in[5];
    const float* Dxz = (const float*)d_in[6];
    const float* Dyy = (const float*)d_in[7];
    const float* Dyz = (const float*)d_in[8];
    const float* Dzz = (const float*)d_in[9];
    float* out = (float*)d_out;

    dim3 grid(N, N / 8, 2);
    dim3 block(N / 4, 8, 1);   // 320 threads = 5 waves; lanes contiguous in z
    hipLaunchKernelGGL(piano_energy_kernel, grid, block, 0, stream,
                       C, Vx, Vy, Vz, Dxx, Dxy, Dxz, Dyy, Dyz, Dzz, out);
}